// Round 5
// baseline (676.474 us; speedup 1.0000x reference)
//
#include <hip/hip_runtime.h>

#define B_ 8
#define S_ 2048
#define M_ 256
#define D_ 512
#define P_ 512
#define H_ 8

#define SCALE 0.044194173824159216f  // 1/sqrt(512)

typedef __attribute__((ext_vector_type(8))) short bf16x8;
typedef __attribute__((ext_vector_type(4))) float f32x4;

static __device__ __forceinline__ float bf2f(short u) {
  union { float f; unsigned int i; } x;
  x.i = ((unsigned int)(unsigned short)u) << 16;
  return x.f;
}
static __device__ __forceinline__ short f2bf(float f) {
  union { float f; unsigned int i; } x;
  x.f = f;
  unsigned int r = (x.i + 0x7FFFu + ((x.i >> 16) & 1u)) >> 16;
  return (short)r;
}

// async global->LDS, 16B per lane; lds base must be wave-uniform
static __device__ __forceinline__ void gll16(const short* g, short* l) {
  __builtin_amdgcn_global_load_lds(
      (const __attribute__((address_space(1))) void*)g,
      (__attribute__((address_space(3))) void*)l, 16, 0, 0);
}

#define LGKM_WAIT() asm volatile("s_waitcnt lgkmcnt(0)" ::: "memory")
#define VMLG_WAIT() asm volatile("s_waitcnt vmcnt(0) lgkmcnt(0)" ::: "memory")
#define RAW_BAR() do { asm volatile("" ::: "memory"); __builtin_amdgcn_s_barrier(); asm volatile("" ::: "memory"); } while (0)

// ---------------------------------------------------------------------------
// fused fp32 -> bf16 cast (RNE) for input_seq and memory_cells
// ---------------------------------------------------------------------------
__global__ __launch_bounds__(256) void cast_both(
    const float* __restrict__ inA, short* __restrict__ outA, int n4A,
    const float* __restrict__ inM, short* __restrict__ outM)
{
  int idx = blockIdx.x * 256 + threadIdx.x;
  const float* in = inA;
  short* out = outA;
  if (idx >= n4A) { idx -= n4A; in = inM; out = outM; }
  float4 v = ((const float4*)in)[idx];
  short o0 = f2bf(v.x), o1 = f2bf(v.y), o2 = f2bf(v.z), o3 = f2bf(v.w);
  uint2 pk;
  pk.x = (unsigned int)(unsigned short)o0 | ((unsigned int)(unsigned short)o1 << 16);
  pk.y = (unsigned int)(unsigned short)o2 | ((unsigned int)(unsigned short)o3 << 16);
  ((uint2*)out)[idx] = pk;
}

// ---------------------------------------------------------------------------
// merged weight transpose+cast for the 512x512 weights
// ---------------------------------------------------------------------------
__global__ __launch_bounds__(256) void wtrans_all(
    const float* __restrict__ Wk, const float* __restrict__ Wv,
    const float* __restrict__ Wq,
    short* __restrict__ WkT, short* __restrict__ WvT, short* __restrict__ WqT)
{
  __shared__ float tile[32][33];
  const int t = threadIdx.x, tx = t & 31, ty = t >> 5;
  const int z = blockIdx.z;
  const float* inp;
  short* outp;
  if (z == 0)      { inp = Wk; outp = WkT; }
  else if (z == 1) { inp = Wv; outp = WvT; }
  else             { inp = Wq + (size_t)(z - 2) * 512 * 512;
                     outp = WqT + (size_t)(z - 2) * 512 * 512; }
  const int n0 = blockIdx.x * 32, k0 = blockIdx.y * 32;
#pragma unroll
  for (int i = 0; i < 4; ++i)
    tile[ty + 8 * i][tx] = inp[(size_t)(k0 + ty + 8 * i) * 512 + n0 + tx];
  __syncthreads();
#pragma unroll
  for (int i = 0; i < 4; ++i)
    outp[(size_t)(n0 + ty + 8 * i) * 512 + k0 + tx] = f2bf(tile[tx][ty + 8 * i]);
}

// ---------------------------------------------------------------------------
// Wo transpose+cast: [4096 k][512 n] fp32 -> [512 n][4096 k] bf16
// ---------------------------------------------------------------------------
__global__ __launch_bounds__(256) void wtrans_wo(
    const float* __restrict__ in, short* __restrict__ out)
{
  __shared__ float tile[32][33];
  const int t = threadIdx.x, tx = t & 31, ty = t >> 5;
  const int n0 = blockIdx.x * 32, k0 = blockIdx.y * 32;
#pragma unroll
  for (int i = 0; i < 4; ++i)
    tile[ty + 8 * i][tx] = in[(size_t)(k0 + ty + 8 * i) * 512 + n0 + tx];
  __syncthreads();
#pragma unroll
  for (int i = 0; i < 4; ++i)
    out[(size_t)(n0 + ty + 8 * i) * 4096 + k0 + tx] = f2bf(tile[tx][ty + 8 * i]);
}

// ---------------------------------------------------------------------------
// 128x128 MFMA GEMM, BK=32, 2-barrier single-buffer K-loop. Used for
// MODE 1 (q projection) and MODE 5 (Wo split-K).
// ---------------------------------------------------------------------------
template<int MODE, int K, int N, int LDA, int LDB>
__global__ __launch_bounds__(256, 3) void gemm128(
    const short* __restrict__ Abase, const short* __restrict__ Bbase,
    const float* __restrict__ bias, void* __restrict__ Cv,
    const size_t aZ, const size_t bZ, const size_t cZ,
    float* __restrict__ Ls,
    const float* __restrict__ eselfp, const short* __restrict__ mvbp)
{
  __shared__ short As[4096];
  __shared__ short Bs[4096];
  const int t = threadIdx.x;
  const int w = t >> 6, lane = t & 63, qd = lane >> 4, ln = lane & 15;
  const int wm = (w & 1) * 64, wn = (w >> 1) * 64;

  const int n0 = blockIdx.x * 128;
  const int m0 = blockIdx.y * 128;
  const int z = blockIdx.z;
  const int bsel = z;

  const short* A  = Abase + (size_t)z * aZ;
  const short* Bp = Bbase + (size_t)bsel * bZ;

  const int rr = t >> 2, g0 = t & 3;
  const int gs0 = g0 ^ ((rr >> 1) & 3);
  const int gs1 = g0 ^ (((rr + 64) >> 1) & 3);
  const short* ga0 = A + (size_t)(m0 + rr) * LDA + gs0 * 8;
  const short* ga1 = A + (size_t)(m0 + rr + 64) * LDA + gs1 * 8;
  const short* gb0 = Bp + (size_t)(n0 + rr) * LDB + gs0 * 8;
  const short* gb1 = Bp + (size_t)(n0 + rr + 64) * LDB + gs1 * 8;

  int aoff[4], boff[4];
#pragma unroll
  for (int mt = 0; mt < 4; ++mt) {
    int r = wm + mt * 16 + ln;
    aoff[mt] = r * 32 + (qd ^ ((r >> 1) & 3)) * 8;
  }
#pragma unroll
  for (int nt = 0; nt < 4; ++nt) {
    int r = wn + nt * 16 + ln;
    boff[nt] = r * 32 + (qd ^ ((r >> 1) & 3)) * 8;
  }

  f32x4 acc[4][4];
#pragma unroll
  for (int mt = 0; mt < 4; ++mt)
#pragma unroll
    for (int nt = 0; nt < 4; ++nt) acc[mt][nt] = (f32x4){0.f, 0.f, 0.f, 0.f};

  for (int kc = 0; kc < K; kc += 32) {
    __syncthreads();
    gll16(ga0 + kc, &As[w * 512]);
    gll16(ga1 + kc, &As[2048 + w * 512]);
    gll16(gb0 + kc, &Bs[w * 512]);
    gll16(gb1 + kc, &Bs[2048 + w * 512]);
    __syncthreads();

    bf16x8 af[4], bfr[4];
#pragma unroll
    for (int mt = 0; mt < 4; ++mt) af[mt] = *(const bf16x8*)&As[aoff[mt]];
#pragma unroll
    for (int nt = 0; nt < 4; ++nt) bfr[nt] = *(const bf16x8*)&Bs[boff[nt]];
#pragma unroll
    for (int mt = 0; mt < 4; ++mt)
#pragma unroll
      for (int nt = 0; nt < 4; ++nt)
        acc[mt][nt] = __builtin_amdgcn_mfma_f32_16x16x32_bf16(af[mt], bfr[nt], acc[mt][nt], 0, 0, 0);
  }

  if constexpr (MODE == 5) {
#pragma unroll
    for (int nt = 0; nt < 4; ++nt) {
      const int col = n0 + wn + nt * 16 + ln;
#pragma unroll
      for (int mt = 0; mt < 4; ++mt)
#pragma unroll
        for (int r = 0; r < 4; ++r) {
          const int row = m0 + wm + mt * 16 + qd * 4 + r;
          ((float*)Cv)[(size_t)z * cZ + (size_t)row * N + col] = acc[mt][nt][r];
        }
    }
  } else {  // MODE 1
#pragma unroll
    for (int nt = 0; nt < 4; ++nt) {
      const int col = n0 + wn + nt * 16 + ln;
      const float bc = bias[512 * z + col];
#pragma unroll
      for (int mt = 0; mt < 4; ++mt)
#pragma unroll
        for (int r = 0; r < 4; ++r) {
          const int row = m0 + wm + mt * 16 + qd * 4 + r;
          const int bidx = row >> 8, ml = row & 255;
          ((short*)Cv)[((size_t)(bidx * H_ + z) * M_ + ml) * N + col] = f2bf(acc[mt][nt][r] + bc);
        }
    }
  }
}

// ---------------------------------------------------------------------------
// QK kernel v5: 256x256 tile, BK=32, NKT=16, 512 thr (8 waves 2Mx4N, wave
// tile 128x64). OCCUPANCY over schedule: LDS cut to 64 KiB (ring-2: A
// 2x8192 sh @0, B 2x8192 sh @16384) + __launch_bounds__(512,4) -> 2 blocks
// resident/CU (grid 512 = exactly 2/CU, 16 waves/CU). Rounds 1-4 proved the
// schedule is not the limiter (4-phase / 1-barrier / ring-3 all 56-67 us,
// MfmaUtil 20-23%, occupancy 18%): at 1 block/CU the per-tile path
// (reads -> MFMA -> drain -> barrier) serializes with nothing to overlap.
// The second block's waves fill the drains/barriers (m97/m114 mechanism).
// Loop: read 12 frags (buf p) | stage t+1 -> buf p^1 (4 gll16) | 32 MFMA |
// vmcnt(0)+lgkm(0) | barrier. Compiler emits counted lgkmcnt between reads
// and MFMA (round-3-verified).
// Swizzle (4-chunk rows): chunk' = c ^ ((row>>1)&3), staged via pre-swizzled
// global source (rule 21); fragment ds_read_b128 conflict-free (measured 0).
// Epilogue: exp + rowsum atomics + TWO-PASS LDS repack (128 rows/pass fits
// 64 KiB) + 16B coalesced stores.
// ---------------------------------------------------------------------------
template<int NKT>
__global__ __launch_bounds__(512, 4) void qk256(
    const short* __restrict__ Abase, const short* __restrict__ Bbase,
    short* __restrict__ Eb, float* __restrict__ Ls)
{
  __shared__ short lds[32768];   // 64 KiB
  const int t = threadIdx.x;
  const int w = t >> 6, lane = t & 63, qd = lane >> 4, ln = lane & 15;
  const int wr = w >> 2, wc = w & 3;
  const int b = blockIdx.x;                       // XCD pin: flat id % 8 == b
  const int n0 = blockIdx.y * 256, m0 = blockIdx.z * 256;

  const short* A  = Abase + (size_t)b * (2048 * 512) + (size_t)m0 * 512;
  const short* Bp = Bbase + (size_t)b * (2048 * 512) + (size_t)n0 * 512;

  // staging source: LDS slot s holds global(row=s>>2, chunk=(s&3)^((row>>1)&3))
  const int srow = t >> 2;
  const int scol = ((t & 3) ^ ((srow >> 1) & 3)) * 8;
  const short* gsA = A  + (size_t)srow * 512 + scol;
  const short* gsB = Bp + (size_t)srow * 512 + scol;

  auto stageA = [&](const short* g, short* l) {
    gll16(g,             l + w * 512);          // rows 0..127
    gll16(g + 128 * 512, l + 4096 + w * 512);   // rows 128..255
  };
  auto stageB = [&](const short* g, short* l) {
    gll16(g,             l + w * 512);
    gll16(g + 128 * 512, l + 4096 + w * 512);
  };

  // fragment offsets: row stride 32 shorts, chunk' = qd ^ ((ln>>1)&3)
  const int fq = (qd ^ ((ln >> 1) & 3)) * 8;
  int aoff[8], boff[4];
#pragma unroll
  for (int mt = 0; mt < 8; ++mt) aoff[mt] = (mt * 16 + ln) * 32 + fq;
#pragma unroll
  for (int j = 0; j < 4; ++j)    boff[j]  = (j * 16 + ln) * 32 + fq;

  f32x4 acc[8][4];
#pragma unroll
  for (int i = 0; i < 8; ++i)
#pragma unroll
    for (int j = 0; j < 4; ++j) acc[i][j] = (f32x4){0.f, 0.f, 0.f, 0.f};

  // ---- prologue: stage tile0 -> buf0, drain, go
  stageA(gsA, &lds[0]);
  stageB(gsB, &lds[16384]);
  asm volatile("s_waitcnt vmcnt(0)" ::: "memory");
  __builtin_amdgcn_s_barrier();

#pragma unroll 1
  for (int kt = 0; kt < NKT; ++kt) {
    const int p = kt & 1;
    short* Ah = &lds[p * 8192 + wr * 4096];             // wave's 128-row half
    short* Bh = &lds[16384 + p * 8192 + wc * 2048];     // wave's 64-row window

    bf16x8 a[8], bfr[4];
#pragma unroll
    for (int j = 0; j < 4; ++j) bfr[j] = *(const bf16x8*)&Bh[boff[j]];
#pragma unroll
    for (int mt = 0; mt < 8; ++mt) a[mt] = *(const bf16x8*)&Ah[aoff[mt]];

    if (kt + 1 < NKT) {
      stageA(gsA + (size_t)(kt + 1) * 32, &lds[(p ^ 1) * 8192]);
      stageB(gsB + (size_t)(kt + 1) * 32, &lds[16384 + (p ^ 1) * 8192]);
    }

    __builtin_amdgcn_s_setprio(1);
#pragma unroll
    for (int mt = 0; mt < 8; ++mt)
#pragma unroll
      for (int j = 0; j < 4; ++j)
        acc[mt][j] = __builtin_amdgcn_mfma_f32_16x16x32_bf16(a[mt], bfr[j], acc[mt][j], 0, 0, 0);
    __builtin_amdgcn_s_setprio(0);

    VMLG_WAIT();
    RAW_BAR();
  }

  // ---- epilogue: exp, rowsum atomics, two-pass LDS repack + stores
#pragma unroll
  for (int i = 0; i < 8; ++i)
#pragma unroll
    for (int j = 0; j < 4; ++j)
#pragma unroll
      for (int r = 0; r < 4; ++r)
        acc[i][j][r] = __expf(acc[i][j][r] * SCALE);
#pragma unroll
  for (int i = 0; i < 8; ++i)
#pragma unroll
    for (int r = 0; r < 4; ++r) {
      float rs = acc[i][0][r] + acc[i][1][r] + acc[i][2][r] + acc[i][3][r];
      rs += __shfl_xor(rs, 1);
      rs += __shfl_xor(rs, 2);
      rs += __shfl_xor(rs, 4);
      rs += __shfl_xor(rs, 8);
      if (ln == 0) {
        const int row = m0 + wr * 128 + i * 16 + qd * 4 + r;
        atomicAdd(&Ls[(size_t)b * 2048 + row], rs);
      }
    }
  short* Cb = Eb + (size_t)b * 2048 * 2048;
#pragma unroll
  for (int pass = 0; pass < 2; ++pass) {
    if (pass) RAW_BAR();     // protect pass0's reads before overwrite
    if (wr == pass) {
#pragma unroll
      for (int i = 0; i < 8; ++i)
#pragma unroll
        for (int j = 0; j < 4; ++j)
#pragma unroll
          for (int r = 0; r < 4; ++r) {
            const int row = i * 16 + qd * 4 + r;        // 0..127 local
            const int col = wc * 64 + j * 16 + ln;
            lds[row * 256 + (col ^ ((row & 7) << 3))] = f2bf(acc[i][j][r]);
          }
    }
    LGKM_WAIT();
    RAW_BAR();
#pragma unroll
    for (int it = 0; it < 8; ++it) {
      const int flat = it * 512 + t;
      const int row = flat >> 5, c = flat & 31;
      bf16x8 v = *(const bf16x8*)&lds[row * 256 + ((c ^ (row & 7)) * 8)];
      *(bf16x8*)(Cb + (size_t)(m0 + pass * 128 + row) * 2048 + n0 + c * 8) = v;
    }
  }
}

// ---------------------------------------------------------------------------
// PV kernel v5: BM=128 x BN=128 tile, BK=64, K=2048 (NKT=32), 512 thr
// (8 waves 2Mx4N, wave tile 64x32), grid (8,4,16) = 512 blocks -> 2/CU
// (16 waves/CU; old BM=256 grid was 256 blocks = 1/CU, latency-bound).
// LDS 64 KiB ring-2: A 2x8192 sh @0 (128x64), B 2x8192 sh @16384 (128x64).
// Loop: read 12 frags | stage t+1 (4 gll16) | 16 MFMA | vmcnt0+lgkm0 | bar.
// Swizzle (8-chunk rows): chunk' = c ^ (row&7), pre-swizzled global source.
// Epilogue: normalize + eself*mv, single-pass repack 128x128 (32 KiB),
// 16B coalesced stores into concat layout.
// ---------------------------------------------------------------------------
template<int NKT>
__global__ __launch_bounds__(512, 4) void pv128(
    const short* __restrict__ Abase, const short* __restrict__ Bbase,
    short* __restrict__ valb, const float* __restrict__ Ls,
    const float* __restrict__ eselfp, const short* __restrict__ mvbp)
{
  __shared__ short lds[32768];   // 64 KiB
  const int t = threadIdx.x;
  const int w = t >> 6, lane = t & 63, qd = lane >> 4, ln = lane & 15;
  const int wr = w >> 2, wc = w & 3;              // 2M x 4N, wave 64x32
  const int b = blockIdx.x;                       // XCD pin
  const int n0 = blockIdx.y * 128;
  const int m0 = blockIdx.z * 128;                // rows of (h*256+m) space

  const short* A  = Abase + (size_t)b * (2048 * 2048) + (size_t)m0 * 2048;
  const short* Bp = Bbase + (size_t)b * (512 * 2048) + (size_t)n0 * 2048;

  // staging source: slot s <- global(row=s>>3, chunk=(s&7)^(row&7))
  const int rr = t >> 3;
  const int sc = ((t & 7) ^ (rr & 7)) * 8;
  const short* gsA = A  + (size_t)rr * 2048 + sc;
  const short* gsB = Bp + (size_t)rr * 2048 + sc;

  auto stageA = [&](const short* g, short* l) {
    gll16(g,              l + w * 512);           // rows 0..63
    gll16(g + 64 * 2048,  l + 4096 + w * 512);    // rows 64..127
  };
  auto stageB = [&](const short* g, short* l) {
    gll16(g,              l + w * 512);
    gll16(g + 64 * 2048,  l + 4096 + w * 512);
  };

  const int cq0 = ((qd    ) ^ (ln & 7)) * 8;
  const int cq1 = ((4 + qd) ^ (ln & 7)) * 8;

  f32x4 acc[4][2];
#pragma unroll
  for (int i = 0; i < 4; ++i)
#pragma unroll
    for (int j = 0; j < 2; ++j) acc[i][j] = (f32x4){0.f, 0.f, 0.f, 0.f};

  // ---- prologue
  stageA(gsA, &lds[0]);
  stageB(gsB, &lds[16384]);
  asm volatile("s_waitcnt vmcnt(0)" ::: "memory");
  __builtin_amdgcn_s_barrier();

#pragma unroll 1
  for (int kt = 0; kt < NKT; ++kt) {
    const int p = kt & 1;
    short* Ah = &lds[p * 8192 + wr * 4096];          // wave's 64-row half
    short* Bh = &lds[16384 + p * 8192 + wc * 2048];  // wave's 32-row window

    bf16x8 a0[4], b0[2];
#pragma unroll
    for (int j = 0; j < 2; ++j)
      b0[j] = *(const bf16x8*)&Bh[(j * 16 + ln) * 64 + cq0];
#pragma unroll
    for (int mt = 0; mt < 4; ++mt)
      a0[mt] = *(const bf16x8*)&Ah[(mt * 16 + ln) * 64 + cq0];

    if (kt + 1 < NKT) {
      stageA(gsA + (size_t)(kt + 1) * 64, &lds[(p ^ 1) * 8192]);
      stageB(gsB + (size_t)(kt + 1) * 64, &lds[16384 + (p ^ 1) * 8192]);
    }

    __builtin_amdgcn_s_setprio(1);
#pragma unroll
    for (int mt = 0; mt < 4; ++mt)
#pragma unroll
      for (int j = 0; j < 2; ++j)
        acc[mt][j] = __builtin_amdgcn_mfma_f32_16x16x32_bf16(a0[mt], b0[j], acc[mt][j], 0, 0, 0);
    __builtin_amdgcn_s_setprio(0);

    bf16x8 a1[4], b1[2];
#pragma unroll
    for (int j = 0; j < 2; ++j)
      b1[j] = *(const bf16x8*)&Bh[(j * 16 + ln) * 64 + cq1];
#pragma unroll
    for (int mt = 0; mt < 4; ++mt)
      a1[mt] = *(const bf16x8*)&Ah[(mt * 16 + ln) * 64 + cq1];
    __builtin_amdgcn_s_setprio(1);
#pragma unroll
    for (int mt = 0; mt < 4; ++mt)
#pragma unroll
      for (int j = 0; j < 2; ++j)
        acc[mt][j] = __builtin_amdgcn_mfma_f32_16x16x32_bf16(a1[mt], b1[j], acc[mt][j], 0, 0, 0);
    __builtin_amdgcn_s_setprio(0);

    VMLG_WAIT();
    RAW_BAR();
  }

  // ---- epilogue: normalize + self-attn term, single-pass repack, stores
#pragma unroll
  for (int mt = 0; mt < 4; ++mt)
#pragma unroll
    for (int r = 0; r < 4; ++r) {
      const int rl = wr * 64 + mt * 16 + qd * 4 + r;   // local row 0..127
      const int R = m0 + rl;                           // h*256+m row
      const float es  = eselfp[(size_t)b * 2048 + R];
      const float inv = 1.f / (es + Ls[(size_t)b * 2048 + R]);
      const short* mvr = mvbp + ((size_t)(b * 256 + (R & 255))) * 512;
#pragma unroll
      for (int j = 0; j < 2; ++j) {
        const int lcol = wc * 32 + j * 16 + ln;
        const float v = (acc[mt][j][r] + es * bf2f(mvr[n0 + lcol])) * inv;
        lds[rl * 128 + (lcol ^ ((rl & 7) << 3))] = f2bf(v);
      }
    }
  LGKM_WAIT();
  RAW_BAR();
#pragma unroll
  for (int it = 0; it < 4; ++it) {
    const int flat = it * 512 + t;
    const int row = flat >> 4, c = flat & 15;
    const int R = m0 + row;
    bf16x8 v = *(const bf16x8*)&lds[row * 128 + ((c ^ (row & 7)) * 8)];
    *(bf16x8*)(valb + ((size_t)(b * 256 + (R & 255))) * 4096
               + (size_t)(R >> 8) * 512 + n0 + c * 8) = v;
  }
}

// ---------------------------------------------------------------------------
// merged K/V projection, BK=32, 2-barrier single-buffer (16 KB LDS).
// ---------------------------------------------------------------------------
template<bool TRANSV>
__global__ __launch_bounds__(256, 3) void proj_kv(
    const short* __restrict__ A,
    const short* __restrict__ WkT, const short* __restrict__ WvT,
    const float* __restrict__ bk, const float* __restrict__ bv,
    short* __restrict__ Ck, short* __restrict__ Cvv)
{
  __shared__ short Sh[8192];
  short* As  = Sh;
  short* Bks = Sh + 4096;
  short* Bvs = Sh + 6144;
  const int t = threadIdx.x;
  const int w = t >> 6, lane = t & 63, qd = lane >> 4, ln = lane & 15;
  const int n0 = blockIdx.x * 64, m0 = blockIdx.y * 128;
  const int wm = (w & 1) * 64, wn2 = (w >> 1) * 32;

  const int rr = t >> 2, g0 = t & 3;
  const int gs0 = g0 ^ ((rr >> 1) & 3);
  const int gs1 = g0 ^ (((rr + 64) >> 1) & 3);
  const short* ga0 = A + (size_t)(m0 + rr) * 512 + gs0 * 8;
  const short* ga1 = A + (size_t)(m0 + rr + 64) * 512 + gs1 * 8;
  const short* gbk = WkT + (size_t)(n0 + rr) * 512 + gs0 * 8;
  const short* gbv = WvT + (size_t)(n0 + rr) * 512 + gs0 * 8;

  int aoff[4], boff[2];
#pragma unroll
  for (int mt = 0; mt < 4; ++mt) {
    int r = wm + mt * 16 + ln;
    aoff[mt] = r * 32 + (qd ^ ((r >> 1) & 3)) * 8;
  }
#pragma unroll
  for (int nt = 0; nt < 2; ++nt) {
    int r = wn2 + nt * 16 + ln;
    boff[nt] = r * 32 + (qd ^ ((r >> 1) & 3)) * 8;
  }

  f32x4 accK[4][2], accV[4][2];
#pragma unroll
  for (int mt = 0; mt < 4; ++mt)
#pragma unroll
    for (int nt = 0; nt < 2; ++nt) {
      accK[mt][nt] = (f32x4){0.f, 0.f, 0.f, 0.f};
      accV[mt][nt] = (f32x4){0.f, 0.f, 0.f, 0.f};
    }

  for (int kc = 0; kc < 512; kc += 32) {
    __syncthreads();
    gll16(ga0 + kc, &As[w * 512]);
    gll16(ga1 + kc, &As[2048 + w * 512]);
    gll16(gbk + kc, &Bks[w * 512]);
    gll16(gbv + kc, &Bvs[w * 512]);
    __syncthreads();

    bf16x8 af[4], bkf[2], bvf[2];
#pragma unroll
    for (int mt = 0; mt < 4; ++mt) af[mt] = *(const bf16x8*)&As[aoff[mt]];
#pragma unroll
    for (int nt = 0; nt < 2; ++nt) {
      bkf[nt] = *(const bf16x8*)&Bks[boff[nt]];
      bvf[nt] = *(const bf16x8*)&Bvs[boff[nt]];
    }
#pragma unroll
    for (int mt = 0; mt < 4; ++mt)
#pragma unroll
      for (int nt = 0; nt < 2; ++nt) {
        accK[mt][nt] = __builtin_amdgcn_mfma_f32_16x16x32_bf16(af[mt], bkf[nt], accK[mt][nt], 0, 0, 0);
        accV[mt][nt] = __builtin_amdgcn_mfma_f32_16x16x32_bf16(af[mt], bvf[nt], accV[mt][nt], 0, 0, 0);
      }
  }

#pragma unroll
  for (int nt = 0; nt < 2; ++nt) {
    const int col = n0 + wn2 + nt * 16 + ln;
    const float bc = bk[col];
#pragma unroll
    for (int mt = 0; mt < 4; ++mt)
#pragma unroll
      for (int r = 0; r < 4; ++r) {
        const int row = m0 + wm + mt * 16 + qd * 4 + r;
        Ck[(size_t)row * 512 + col] = f2bf(accK[mt][nt][r] + bc);
      }
  }

  if constexpr (!TRANSV) {
#pragma unroll
    for (int nt = 0; nt < 2; ++nt) {
      const int col = n0 + wn2 + nt * 16 + ln;
      const float bc = bv[col];
#pragma unroll
      for (int mt = 0; mt < 4; ++mt)
#pragma unroll
        for (int r = 0; r < 4; ++r) {
          const int row = m0 + wm + mt * 16 + qd * 4 + r;
          Cvv[(size_t)row * 512 + col] = f2bf(accV[mt][nt][r] + bc);
        }
    }
  } else {
    __syncthreads();
    short* ep = &Sh[w * 1280];
    const int lr = lane >> 1, lc16 = (lane & 1) * 16;
#pragma unroll
    for (int pass = 0; pass < 2; ++pass) {
#pragma unroll
      for (int mh = 0; mh < 2; ++mh) {
        const int mt = pass * 2 + mh;
#pragma unroll
        for (int nt = 0; nt < 2; ++nt) {
          const float bc = bv[n0 + wn2 + nt * 16 + ln];
#pragma unroll
          for (int r = 0; r < 4; ++r)
            ep[(nt * 16 + ln) * 40 + mh * 16 + qd * 4 + r] = f2bf(accV[mt][nt][r] + bc);
        }
      }
      LGKM_WAIT();
      const int srow0 = m0 + wm + pass * 32;
      const int bidx = srow0 >> 11;
      const int sloc = (srow0 & 2047) + lc16;
      const int pcol = n0 + wn2 + lr;
      short* outp = Cvv + (size_t)bidx * P_ * S_ + (size_t)pcol * S_ + sloc;
      *(bf16x8*)outp = *(const bf16x8*)&ep[lr * 40 + lc16];
      *(bf16x8*)(outp + 8) = *(const bf16x8*)&ep[lr * 40 + lc16 + 8];
      LGKM_WAIT();
    }
  }
}

// ---------------------------------------------------------------------------
// split-K reduce for Wo: out = sum_z partial[z] + bo[col], fp32
// ---------------------------------------------------------------------------
__global__ __launch_bounds__(256) void reduce_wo(
    const float* __restrict__ partial, const float* __restrict__ bo,
    float* __restrict__ out)
{
  const int idx4 = blockIdx.x * 256 + threadIdx.x;
  float4 s = ((const float4*)bo)[idx4 & 127];
#pragma unroll
  for (int zz = 0; zz < 4; ++zz) {
    float4 p = ((const float4*)partial)[(size_t)zz * 262144 + idx4];
    s.x += p.x; s.y += p.y; s.z += p.z; s.w += p.w;
  }
  ((float4*)out)[idx4] = s;
}

// ---------------------------------------------------------------------------
// self-score + Ls zeroing
// ---------------------------------------------------------------------------
__global__ __launch_bounds__(256) void selfscore(
    const short* __restrict__ qb, const short* __restrict__ mkb,
    float* __restrict__ eself, float* __restrict__ Ls)
{
  const int z = blockIdx.x, t = threadIdx.x;
  const short* qr = qb + ((size_t)z * M_ + t) * P_;
  const short* mr = mkb + ((size_t)(z >> 3) * M_ + t) * P_;
  float s = 0.f;
#pragma unroll 8
  for (int c = 0; c < P_; c += 8) {
    bf16x8 qv = *(const bf16x8*)(qr + c);
    bf16x8 mv = *(const bf16x8*)(mr + c);
#pragma unroll
    for (int j = 0; j < 8; ++j) s += bf2f(qv[j]) * bf2f(mv[j]);
  }
  eself[(size_t)z * M_ + t] = __expf(s * SCALE);
  Ls[(size_t)z * M_ + t] = 0.f;
}

// ---------------------------------------------------------------------------
extern "C" void kernel_launch(void* const* d_in, const int* in_sizes, int n_in,
                              void* d_out, int out_size, void* d_ws, size_t ws_size,
                              hipStream_t stream) {
  const float* input_seq = (const float*)d_in[0];
  const float* memcells  = (const float*)d_in[1];
  const float* Wk = (const float*)d_in[2];
  const float* bk = (const float*)d_in[3];
  const float* Wv = (const float*)d_in[4];
  const float* bv = (const float*)d_in[5];
  const float* Wq = (const float*)d_in[6];
  const float* bq = (const float*)d_in[7];
  const float* Wo = (const float*)d_in[8];
  const float* bo = (const float*)d_in[9];
  float* out = (float*)d_out;

  short* ws = (short*)d_ws;
  size_t o = 0;
  short* valb = ws + o; o += (size_t)B_ * M_ * H_ * P_;      // 8388608
  short* WoT  = ws + o; o += (size_t)(H_ * P_) * P_;          // 2097152
  short* mvb  = ws + o; o += (size_t)B_ * M_ * P_;            // 1048576
  short* mkb  = ws + o; o += (size_t)B_ * M_ * P_;            // 1048576
  short* qb   = ws + o; o += (size_t)B_ * H_ * M_ * P_;       // 8388608
  short* ivT  = ws + o; o += (size_t)B_ * P_ * S_;            // 8388608
  short* ikb  = ws + o; o += (size_t)B_ * S_ * P_;            // 8388608
  float* partial = (float*)(ws + o); o += (size_t)B_ * H_ * M_ * P_;  // 16 MB
  float* eself = (float*)(ws + o); o += 2 * (size_t)B_ * H_ * M_;
  float* Ls    = (float*)(ws + o); o += 2 * (size_t)B_ * H_ * M_;
  short* region2 = ws + o;                                    // Eb region (64 MB)
  short* Ab  = region2;
  short* Mb  = Ab + (size_t)B_ * S_ * D_;
  short* WkT = Mb + (size_t)B_ * M_ * D_;
  short* WvT = WkT + (size_t)D_ * P_;
  short* WqT = WvT + (size_t)D_ * P_;
  short* Eb  = region2;   // overlaps the above (all dead before E is written)

  dim3 blk(256);

  const int n4A = B_ * S_ * D_ / 4;
  const int n4M = B_ * M_ * D_ / 4;
  cast_both<<<dim3((n4A + n4M) / 256), blk, 0, stream>>>(input_seq, Ab, n4A, memcells, Mb);
  wtrans_all<<<dim3(16, 16, 10), blk, 0, stream>>>(Wk, Wv, Wq, WkT, WvT, WqT);
  wtrans_wo<<<dim3(16, 128), blk, 0, stream>>>(Wo, WoT);

  proj_kv<true><<<dim3(8, 128), blk, 0, stream>>>(Ab, WkT, WvT, bk, bv, ikb, ivT);
  proj_kv<false><<<dim3(8, 16), blk, 0, stream>>>(Mb, WkT, WvT, bk, bv, mkb, mvb);

  // q projection: MODE 1, z = h
  gemm128<1, 512, 512, 512, 512><<<dim3(4, 16, 8), blk, 0, stream>>>(
      Mb, WqT, bq, qb, 0, (size_t)D_ * P_, 0, nullptr, nullptr, nullptr);

  // eself + zero Ls (before QK's atomics)
  selfscore<<<dim3(64), blk, 0, stream>>>(qb, mkb, eself, Ls);

  // E = exp(scale * q @ ik^T) + fused row-sum; per-batch 2048x2048, K=512
  // 512 blocks x 64 KiB LDS -> 2 blocks/CU
  qk256<16><<<dim3(8, 8, 8), dim3(512), 0, stream>>>(qb, ikb, Eb, Ls);

  // val = normalize(E @ iv + eself*mv), concat layout; per-batch 2048x512,
  // K=2048; BM=128 x BN=128 -> 512 blocks, 2/CU
  pv128<32><<<dim3(8, 4, 16), dim3(512), 0, stream>>>(Eb, ivT, valb, Ls, eself, mvb);

  // Wo: split-K=4 partials, then reduce+bias
  gemm128<5, 1024, 512, 4096, 4096><<<dim3(4, 16, 4), blk, 0, stream>>>(
      valb, WoT, nullptr, partial, 1024, 1024,
      (size_t)2048 * 512, nullptr, nullptr, nullptr);
  reduce_wo<<<dim3(1024), blk, 0, stream>>>(partial, bo, out);
}

// Round 6
// 321.017 us; speedup vs baseline: 2.1073x; 2.1073x over previous
//
#include <hip/hip_runtime.h>

#define B_ 8
#define S_ 2048
#define M_ 256
#define D_ 512
#define P_ 512
#define H_ 8

#define SCALE 0.044194173824159216f  // 1/sqrt(512)

typedef __attribute__((ext_vector_type(8))) short bf16x8;
typedef __attribute__((ext_vector_type(4))) float f32x4;

static __device__ __forceinline__ float bf2f(short u) {
  union { float f; unsigned int i; } x;
  x.i = ((unsigned int)(unsigned short)u) << 16;
  return x.f;
}
static __device__ __forceinline__ short f2bf(float f) {
  union { float f; unsigned int i; } x;
  x.f = f;
  unsigned int r = (x.i + 0x7FFFu + ((x.i >> 16) & 1u)) >> 16;
  return (short)r;
}

// async global->LDS, 16B per lane; lds base must be wave-uniform
static __device__ __forceinline__ void gll16(const short* g, short* l) {
  __builtin_amdgcn_global_load_lds(
      (const __attribute__((address_space(1))) void*)g,
      (__attribute__((address_space(3))) void*)l, 16, 0, 0);
}

#define LGKM_WAIT() asm volatile("s_waitcnt lgkmcnt(0)" ::: "memory")
#define VMLG_WAIT() asm volatile("s_waitcnt vmcnt(0) lgkmcnt(0)" ::: "memory")
#define RAW_BAR() do { asm volatile("" ::: "memory"); __builtin_amdgcn_s_barrier(); asm volatile("" ::: "memory"); } while (0)

// ---------------------------------------------------------------------------
// fused fp32 -> bf16 cast (RNE) for input_seq and memory_cells
// ---------------------------------------------------------------------------
__global__ __launch_bounds__(256) void cast_both(
    const float* __restrict__ inA, short* __restrict__ outA, int n4A,
    const float* __restrict__ inM, short* __restrict__ outM)
{
  int idx = blockIdx.x * 256 + threadIdx.x;
  const float* in = inA;
  short* out = outA;
  if (idx >= n4A) { idx -= n4A; in = inM; out = outM; }
  float4 v = ((const float4*)in)[idx];
  short o0 = f2bf(v.x), o1 = f2bf(v.y), o2 = f2bf(v.z), o3 = f2bf(v.w);
  uint2 pk;
  pk.x = (unsigned int)(unsigned short)o0 | ((unsigned int)(unsigned short)o1 << 16);
  pk.y = (unsigned int)(unsigned short)o2 | ((unsigned int)(unsigned short)o3 << 16);
  ((uint2*)out)[idx] = pk;
}

// ---------------------------------------------------------------------------
// merged weight transpose+cast for the 512x512 weights
// ---------------------------------------------------------------------------
__global__ __launch_bounds__(256) void wtrans_all(
    const float* __restrict__ Wk, const float* __restrict__ Wv,
    const float* __restrict__ Wq,
    short* __restrict__ WkT, short* __restrict__ WvT, short* __restrict__ WqT)
{
  __shared__ float tile[32][33];
  const int t = threadIdx.x, tx = t & 31, ty = t >> 5;
  const int z = blockIdx.z;
  const float* inp;
  short* outp;
  if (z == 0)      { inp = Wk; outp = WkT; }
  else if (z == 1) { inp = Wv; outp = WvT; }
  else             { inp = Wq + (size_t)(z - 2) * 512 * 512;
                     outp = WqT + (size_t)(z - 2) * 512 * 512; }
  const int n0 = blockIdx.x * 32, k0 = blockIdx.y * 32;
#pragma unroll
  for (int i = 0; i < 4; ++i)
    tile[ty + 8 * i][tx] = inp[(size_t)(k0 + ty + 8 * i) * 512 + n0 + tx];
  __syncthreads();
#pragma unroll
  for (int i = 0; i < 4; ++i)
    outp[(size_t)(n0 + ty + 8 * i) * 512 + k0 + tx] = f2bf(tile[tx][ty + 8 * i]);
}

// ---------------------------------------------------------------------------
// Wo transpose+cast: [4096 k][512 n] fp32 -> [512 n][4096 k] bf16
// ---------------------------------------------------------------------------
__global__ __launch_bounds__(256) void wtrans_wo(
    const float* __restrict__ in, short* __restrict__ out)
{
  __shared__ float tile[32][33];
  const int t = threadIdx.x, tx = t & 31, ty = t >> 5;
  const int n0 = blockIdx.x * 32, k0 = blockIdx.y * 32;
#pragma unroll
  for (int i = 0; i < 4; ++i)
    tile[ty + 8 * i][tx] = in[(size_t)(k0 + ty + 8 * i) * 512 + n0 + tx];
  __syncthreads();
#pragma unroll
  for (int i = 0; i < 4; ++i)
    out[(size_t)(n0 + ty + 8 * i) * 4096 + k0 + tx] = f2bf(tile[tx][ty + 8 * i]);
}

// ---------------------------------------------------------------------------
// 128x128 MFMA GEMM, BK=32, 2-barrier single-buffer K-loop. Used for
// MODE 1 (q projection) and MODE 5 (Wo split-K).
// ---------------------------------------------------------------------------
template<int MODE, int K, int N, int LDA, int LDB>
__global__ __launch_bounds__(256, 3) void gemm128(
    const short* __restrict__ Abase, const short* __restrict__ Bbase,
    const float* __restrict__ bias, void* __restrict__ Cv,
    const size_t aZ, const size_t bZ, const size_t cZ,
    float* __restrict__ Ls,
    const float* __restrict__ eselfp, const short* __restrict__ mvbp)
{
  __shared__ short As[4096];
  __shared__ short Bs[4096];
  const int t = threadIdx.x;
  const int w = t >> 6, lane = t & 63, qd = lane >> 4, ln = lane & 15;
  const int wm = (w & 1) * 64, wn = (w >> 1) * 64;

  const int n0 = blockIdx.x * 128;
  const int m0 = blockIdx.y * 128;
  const int z = blockIdx.z;
  const int bsel = z;

  const short* A  = Abase + (size_t)z * aZ;
  const short* Bp = Bbase + (size_t)bsel * bZ;

  const int rr = t >> 2, g0 = t & 3;
  const int gs0 = g0 ^ ((rr >> 1) & 3);
  const int gs1 = g0 ^ (((rr + 64) >> 1) & 3);
  const short* ga0 = A + (size_t)(m0 + rr) * LDA + gs0 * 8;
  const short* ga1 = A + (size_t)(m0 + rr + 64) * LDA + gs1 * 8;
  const short* gb0 = Bp + (size_t)(n0 + rr) * LDB + gs0 * 8;
  const short* gb1 = Bp + (size_t)(n0 + rr + 64) * LDB + gs1 * 8;

  int aoff[4], boff[4];
#pragma unroll
  for (int mt = 0; mt < 4; ++mt) {
    int r = wm + mt * 16 + ln;
    aoff[mt] = r * 32 + (qd ^ ((r >> 1) & 3)) * 8;
  }
#pragma unroll
  for (int nt = 0; nt < 4; ++nt) {
    int r = wn + nt * 16 + ln;
    boff[nt] = r * 32 + (qd ^ ((r >> 1) & 3)) * 8;
  }

  f32x4 acc[4][4];
#pragma unroll
  for (int mt = 0; mt < 4; ++mt)
#pragma unroll
    for (int nt = 0; nt < 4; ++nt) acc[mt][nt] = (f32x4){0.f, 0.f, 0.f, 0.f};

  for (int kc = 0; kc < K; kc += 32) {
    __syncthreads();
    gll16(ga0 + kc, &As[w * 512]);
    gll16(ga1 + kc, &As[2048 + w * 512]);
    gll16(gb0 + kc, &Bs[w * 512]);
    gll16(gb1 + kc, &Bs[2048 + w * 512]);
    __syncthreads();

    bf16x8 af[4], bfr[4];
#pragma unroll
    for (int mt = 0; mt < 4; ++mt) af[mt] = *(const bf16x8*)&As[aoff[mt]];
#pragma unroll
    for (int nt = 0; nt < 4; ++nt) bfr[nt] = *(const bf16x8*)&Bs[boff[nt]];
#pragma unroll
    for (int mt = 0; mt < 4; ++mt)
#pragma unroll
      for (int nt = 0; nt < 4; ++nt)
        acc[mt][nt] = __builtin_amdgcn_mfma_f32_16x16x32_bf16(af[mt], bfr[nt], acc[mt][nt], 0, 0, 0);
  }

  if constexpr (MODE == 5) {
#pragma unroll
    for (int nt = 0; nt < 4; ++nt) {
      const int col = n0 + wn + nt * 16 + ln;
#pragma unroll
      for (int mt = 0; mt < 4; ++mt)
#pragma unroll
        for (int r = 0; r < 4; ++r) {
          const int row = m0 + wm + mt * 16 + qd * 4 + r;
          ((float*)Cv)[(size_t)z * cZ + (size_t)row * N + col] = acc[mt][nt][r];
        }
    }
  } else {  // MODE 1
#pragma unroll
    for (int nt = 0; nt < 4; ++nt) {
      const int col = n0 + wn + nt * 16 + ln;
      const float bc = bias[512 * z + col];
#pragma unroll
      for (int mt = 0; mt < 4; ++mt)
#pragma unroll
        for (int r = 0; r < 4; ++r) {
          const int row = m0 + wm + mt * 16 + qd * 4 + r;
          const int bidx = row >> 8, ml = row & 255;
          ((short*)Cv)[((size_t)(bidx * H_ + z) * M_ + ml) * N + col] = f2bf(acc[mt][nt][r] + bc);
        }
    }
  }
}

// ---------------------------------------------------------------------------
// QK kernel v6 (qk128): 128x128 tile, BK=32, NKT=16, 256 thr (4 waves 2Mx2N,
// wave tile 64x64, acc[4][4]=64 VGPR). MULTI-BLOCK occupancy: LDS 32 KiB
// (A dbuf 2x4096 sh @0, B dbuf 2x4096 sh @8192) + ~145 VGPR ->
// 3 blocks/CU (12 waves/CU), grid (8,16,16)=2048 blocks (8 avail/CU).
// Rounds 1-5 showed every 8-wave 256^2 variant pins at 1 block/CU
// (acc[8][4]=128 VGPR forces 2 waves/SIMD; launch_bounds(512,4) spilled
// catastrophically in r5). 4-wave blocks with acc[4][4] are the only
// geometry where 3+ INDEPENDENT barrier groups fit: one block's MFMA
// covers another's staging drains (m97/m114; m102's 320->833 TF shape
// curve is exactly grid-blocks/CU). launch_bounds(256,3): budget 170,
// no spill risk.
// Loop (proven r3 shape): read 8 frags (buf p) | stage t+1 -> p^1
// (4 gll16) | 16 MFMA | vmcnt0+lgkm0 | barrier.
// Swizzle (4-chunk rows, r4-verified 0 conflicts): chunk' = c^((row>>1)&3),
// staged via pre-swizzled global source (rule 21); fragment granules 2-way.
// Epilogue: exp + rowsum atomics (per-wave 64-col partial, 2 atomics/row
// per block) + 32 KiB LDS repack (dbuf dead) + 256B coalesced stores.
// ---------------------------------------------------------------------------
template<int NKT>
__global__ __launch_bounds__(256, 3) void qk128(
    const short* __restrict__ Abase, const short* __restrict__ Bbase,
    short* __restrict__ Eb, float* __restrict__ Ls)
{
  __shared__ short lds[16384];   // 32 KiB
  const int t = threadIdx.x;
  const int w = t >> 6, lane = t & 63, qd = lane >> 4, ln = lane & 15;
  const int wrp = w & 1, wcp = w >> 1;            // 2M x 2N
  const int b = blockIdx.x;                       // XCD pin: flat id % 8 == b
  const int n0 = blockIdx.y * 128, m0 = blockIdx.z * 128;

  const short* A  = Abase + (size_t)b * (2048 * 512) + (size_t)m0 * 512;
  const short* Bp = Bbase + (size_t)b * (2048 * 512) + (size_t)n0 * 512;

  // staging source: slot s=(w*64+lane) <- global(row=s>>2, chunk=(s&3)^((row>>1)&3))
  const int srow = t >> 2;
  const int scol = ((t & 3) ^ ((srow >> 1) & 3)) * 8;
  const short* gsA = A  + (size_t)srow * 512 + scol;
  const short* gsB = Bp + (size_t)srow * 512 + scol;

  auto stage = [&](const short* g, short* l) {   // 128 rows x 32 k
    gll16(g,            l + w * 512);            // rows 0..63
    gll16(g + 64 * 512, l + 2048 + w * 512);     // rows 64..127
  };

  // fragment offsets: row stride 32 shorts, chunk' = qd ^ ((ln>>1)&3)
  const int fq = (qd ^ ((ln >> 1) & 3)) * 8;
  int aoff[4], boff[4];
#pragma unroll
  for (int mt = 0; mt < 4; ++mt) aoff[mt] = (wrp * 64 + mt * 16 + ln) * 32 + fq;
#pragma unroll
  for (int nt = 0; nt < 4; ++nt) boff[nt] = (wcp * 64 + nt * 16 + ln) * 32 + fq;

  f32x4 acc[4][4];
#pragma unroll
  for (int i = 0; i < 4; ++i)
#pragma unroll
    for (int j = 0; j < 4; ++j) acc[i][j] = (f32x4){0.f, 0.f, 0.f, 0.f};

  // ---- prologue: stage tile0 -> buf0, drain, go
  stage(gsA, &lds[0]);
  stage(gsB, &lds[8192]);
  asm volatile("s_waitcnt vmcnt(0)" ::: "memory");
  __builtin_amdgcn_s_barrier();

#pragma unroll 1
  for (int kt = 0; kt < NKT; ++kt) {
    const int p = kt & 1;
    short* Ah = &lds[p * 4096];
    short* Bh = &lds[8192 + p * 4096];

    bf16x8 a[4], bfr[4];
#pragma unroll
    for (int nt = 0; nt < 4; ++nt) bfr[nt] = *(const bf16x8*)&Bh[boff[nt]];
#pragma unroll
    for (int mt = 0; mt < 4; ++mt) a[mt] = *(const bf16x8*)&Ah[aoff[mt]];

    if (kt + 1 < NKT) {
      stage(gsA + (size_t)(kt + 1) * 32, &lds[(p ^ 1) * 4096]);
      stage(gsB + (size_t)(kt + 1) * 32, &lds[8192 + (p ^ 1) * 4096]);
    }

    __builtin_amdgcn_s_setprio(1);
#pragma unroll
    for (int mt = 0; mt < 4; ++mt)
#pragma unroll
      for (int nt = 0; nt < 4; ++nt)
        acc[mt][nt] = __builtin_amdgcn_mfma_f32_16x16x32_bf16(a[mt], bfr[nt], acc[mt][nt], 0, 0, 0);
    __builtin_amdgcn_s_setprio(0);

    VMLG_WAIT();
    RAW_BAR();
  }

  // ---- epilogue: exp, per-wave rowsum atomics, LDS repack, 256B stores
#pragma unroll
  for (int i = 0; i < 4; ++i)
#pragma unroll
    for (int j = 0; j < 4; ++j)
#pragma unroll
      for (int r = 0; r < 4; ++r)
        acc[i][j][r] = __expf(acc[i][j][r] * SCALE);
#pragma unroll
  for (int i = 0; i < 4; ++i)
#pragma unroll
    for (int r = 0; r < 4; ++r) {
      float rs = acc[i][0][r] + acc[i][1][r] + acc[i][2][r] + acc[i][3][r];
      rs += __shfl_xor(rs, 1);
      rs += __shfl_xor(rs, 2);
      rs += __shfl_xor(rs, 4);
      rs += __shfl_xor(rs, 8);
      if (ln == 0) {
        const int row = m0 + wrp * 64 + i * 16 + qd * 4 + r;
        atomicAdd(&Ls[(size_t)b * 2048 + row], rs);
      }
    }
  // repack 128x128 bf16 into dead dbuf: lds[row*128 + (col ^ ((row&7)<<3))]
#pragma unroll
  for (int i = 0; i < 4; ++i)
#pragma unroll
    for (int j = 0; j < 4; ++j)
#pragma unroll
      for (int r = 0; r < 4; ++r) {
        const int row = wrp * 64 + i * 16 + qd * 4 + r;
        const int col = wcp * 64 + j * 16 + ln;
        lds[row * 128 + (col ^ ((row & 7) << 3))] = f2bf(acc[i][j][r]);
      }
  LGKM_WAIT();
  RAW_BAR();
  short* Cb = Eb + (size_t)b * 2048 * 2048;
#pragma unroll
  for (int it = 0; it < 8; ++it) {
    const int flat = it * 256 + t;
    const int row = flat >> 4, c = flat & 15;
    bf16x8 v = *(const bf16x8*)&lds[row * 128 + ((c ^ (row & 7)) * 8)];
    *(bf16x8*)(Cb + (size_t)(m0 + row) * 2048 + n0 + c * 8) = v;
  }
}

// ---------------------------------------------------------------------------
// PV kernel v6 (pv64): 128(rows)x64(p) tile, BK=64, K=2048 (NKT=32),
// 256 thr (4 waves 2Mx2N, wave tile 64x32, acc[4][2]=32 VGPR).
// LDS 48 KiB (A dbuf 2x8192 sh @0, B dbuf 2x4096 sh @16384) -> 3 blocks/CU
// (12 waves/CU); grid (8,8,16)=1024 blocks (4 avail/CU). Same multi-block
// rationale as qk128; same r3 loop shape; 8-chunk swizzle chunk'=c^(row&7)
// (r2-r4 verified 0 conflicts) via pre-swizzled global source.
// Epilogue: normalize + eself*mv, 16 KiB repack, 128B coalesced stores
// into concat layout.
// ---------------------------------------------------------------------------
template<int NKT>
__global__ __launch_bounds__(256, 3) void pv64(
    const short* __restrict__ Abase, const short* __restrict__ Bbase,
    short* __restrict__ valb, const float* __restrict__ Ls,
    const float* __restrict__ eselfp, const short* __restrict__ mvbp)
{
  __shared__ short lds[24576];   // 48 KiB
  const int t = threadIdx.x;
  const int w = t >> 6, lane = t & 63, qd = lane >> 4, ln = lane & 15;
  const int wrp = w & 1, wcp = w >> 1;            // 2M x 2N
  const int b = blockIdx.x;                       // XCD pin
  const int n0 = blockIdx.y * 64;                 // p-cols
  const int m0 = blockIdx.z * 128;                // rows of (h*256+m) space

  const short* A  = Abase + (size_t)b * (2048 * 2048) + (size_t)m0 * 2048;
  const short* Bp = Bbase + (size_t)b * (512 * 2048) + (size_t)n0 * 2048;

  // staging source (8-chunk rows): slot s <- global(row=s>>3, chunk=(s&7)^(row&7))
  const int rr = t >> 3;                          // 0..31
  const int sc = ((t & 7) ^ (rr & 7)) * 8;
  const short* gsA = A  + (size_t)rr * 2048 + sc;
  const short* gsB = Bp + (size_t)rr * 2048 + sc;

  auto stageA = [&](const short* g, short* l) {   // 128 rows x 64 k, 4 calls
#pragma unroll
    for (int kq = 0; kq < 4; ++kq)
      gll16(g + (size_t)(32 * kq) * 2048, l + kq * 2048 + w * 512);
  };
  auto stageB = [&](const short* g, short* l) {   // 64 rows x 64 k, 2 calls
#pragma unroll
    for (int kq = 0; kq < 2; ++kq)
      gll16(g + (size_t)(32 * kq) * 2048, l + kq * 2048 + w * 512);
  };

  const int cq0 = ((qd    ) ^ (ln & 7)) * 8;
  const int cq1 = ((4 + qd) ^ (ln & 7)) * 8;

  f32x4 acc[4][2];
#pragma unroll
  for (int i = 0; i < 4; ++i)
#pragma unroll
    for (int j = 0; j < 2; ++j) acc[i][j] = (f32x4){0.f, 0.f, 0.f, 0.f};

  // ---- prologue
  stageA(gsA, &lds[0]);
  stageB(gsB, &lds[16384]);
  asm volatile("s_waitcnt vmcnt(0)" ::: "memory");
  __builtin_amdgcn_s_barrier();

#pragma unroll 1
  for (int kt = 0; kt < NKT; ++kt) {
    const int p = kt & 1;
    short* Ah = &lds[p * 8192 + wrp * 4096];          // wave's 64-row half
    short* Bh = &lds[16384 + p * 4096 + wcp * 2048];  // wave's 32-row window

    bf16x8 a[4][2], bfr[2][2];
#pragma unroll
    for (int nt = 0; nt < 2; ++nt) {
      bfr[nt][0] = *(const bf16x8*)&Bh[(nt * 16 + ln) * 64 + cq0];
      bfr[nt][1] = *(const bf16x8*)&Bh[(nt * 16 + ln) * 64 + cq1];
    }
#pragma unroll
    for (int mt = 0; mt < 4; ++mt) {
      a[mt][0] = *(const bf16x8*)&Ah[(mt * 16 + ln) * 64 + cq0];
      a[mt][1] = *(const bf16x8*)&Ah[(mt * 16 + ln) * 64 + cq1];
    }

    if (kt + 1 < NKT) {
      stageA(gsA + (size_t)(kt + 1) * 64, &lds[(p ^ 1) * 8192]);
      stageB(gsB + (size_t)(kt + 1) * 64, &lds[16384 + (p ^ 1) * 4096]);
    }

    __builtin_amdgcn_s_setprio(1);
#pragma unroll
    for (int kk = 0; kk < 2; ++kk)
#pragma unroll
      for (int mt = 0; mt < 4; ++mt)
#pragma unroll
        for (int nt = 0; nt < 2; ++nt)
          acc[mt][nt] = __builtin_amdgcn_mfma_f32_16x16x32_bf16(a[mt][kk], bfr[nt][kk], acc[mt][nt], 0, 0, 0);
    __builtin_amdgcn_s_setprio(0);

    VMLG_WAIT();
    RAW_BAR();
  }

  // ---- epilogue: normalize + self-attn term, 16 KiB repack, stores
#pragma unroll
  for (int mt = 0; mt < 4; ++mt)
#pragma unroll
    for (int r = 0; r < 4; ++r) {
      const int rl = wrp * 64 + mt * 16 + qd * 4 + r;   // local row 0..127
      const int R = m0 + rl;                            // h*256+m row
      const float es  = eselfp[(size_t)b * 2048 + R];
      const float inv = 1.f / (es + Ls[(size_t)b * 2048 + R]);
      const short* mvr = mvbp + ((size_t)(b * 256 + (R & 255))) * 512;
#pragma unroll
      for (int j = 0; j < 2; ++j) {
        const int lcol = wcp * 32 + j * 16 + ln;
        const float v = (acc[mt][j][r] + es * bf2f(mvr[n0 + lcol])) * inv;
        lds[rl * 64 + (lcol ^ ((rl & 7) << 3))] = f2bf(v);
      }
    }
  LGKM_WAIT();
  RAW_BAR();
#pragma unroll
  for (int it = 0; it < 4; ++it) {
    const int flat = it * 256 + t;
    const int row = flat >> 3, c = flat & 7;
    const int R = m0 + row;
    bf16x8 v = *(const bf16x8*)&lds[row * 64 + ((c ^ (row & 7)) * 8)];
    *(bf16x8*)(valb + ((size_t)(b * 256 + (R & 255))) * 4096
               + (size_t)(R >> 8) * 512 + n0 + c * 8) = v;
  }
}

// ---------------------------------------------------------------------------
// merged K/V projection, BK=32, 2-barrier single-buffer (16 KB LDS).
// ---------------------------------------------------------------------------
template<bool TRANSV>
__global__ __launch_bounds__(256, 3) void proj_kv(
    const short* __restrict__ A,
    const short* __restrict__ WkT, const short* __restrict__ WvT,
    const float* __restrict__ bk, const float* __restrict__ bv,
    short* __restrict__ Ck, short* __restrict__ Cvv)
{
  __shared__ short Sh[8192];
  short* As  = Sh;
  short* Bks = Sh + 4096;
  short* Bvs = Sh + 6144;
  const int t = threadIdx.x;
  const int w = t >> 6, lane = t & 63, qd = lane >> 4, ln = lane & 15;
  const int n0 = blockIdx.x * 64, m0 = blockIdx.y * 128;
  const int wm = (w & 1) * 64, wn2 = (w >> 1) * 32;

  const int rr = t >> 2, g0 = t & 3;
  const int gs0 = g0 ^ ((rr >> 1) & 3);
  const int gs1 = g0 ^ (((rr + 64) >> 1) & 3);
  const short* ga0 = A + (size_t)(m0 + rr) * 512 + gs0 * 8;
  const short* ga1 = A + (size_t)(m0 + rr + 64) * 512 + gs1 * 8;
  const short* gbk = WkT + (size_t)(n0 + rr) * 512 + gs0 * 8;
  const short* gbv = WvT + (size_t)(n0 + rr) * 512 + gs0 * 8;

  int aoff[4], boff[2];
#pragma unroll
  for (int mt = 0; mt < 4; ++mt) {
    int r = wm + mt * 16 + ln;
    aoff[mt] = r * 32 + (qd ^ ((r >> 1) & 3)) * 8;
  }
#pragma unroll
  for (int nt = 0; nt < 2; ++nt) {
    int r = wn2 + nt * 16 + ln;
    boff[nt] = r * 32 + (qd ^ ((r >> 1) & 3)) * 8;
  }

  f32x4 accK[4][2], accV[4][2];
#pragma unroll
  for (int mt = 0; mt < 4; ++mt)
#pragma unroll
    for (int nt = 0; nt < 2; ++nt) {
      accK[mt][nt] = (f32x4){0.f, 0.f, 0.f, 0.f};
      accV[mt][nt] = (f32x4){0.f, 0.f, 0.f, 0.f};
    }

  for (int kc = 0; kc < 512; kc += 32) {
    __syncthreads();
    gll16(ga0 + kc, &As[w * 512]);
    gll16(ga1 + kc, &As[2048 + w * 512]);
    gll16(gbk + kc, &Bks[w * 512]);
    gll16(gbv + kc, &Bvs[w * 512]);
    __syncthreads();

    bf16x8 af[4], bkf[2], bvf[2];
#pragma unroll
    for (int mt = 0; mt < 4; ++mt) af[mt] = *(const bf16x8*)&As[aoff[mt]];
#pragma unroll
    for (int nt = 0; nt < 2; ++nt) {
      bkf[nt] = *(const bf16x8*)&Bks[boff[nt]];
      bvf[nt] = *(const bf16x8*)&Bvs[boff[nt]];
    }
#pragma unroll
    for (int mt = 0; mt < 4; ++mt)
#pragma unroll
      for (int nt = 0; nt < 2; ++nt) {
        accK[mt][nt] = __builtin_amdgcn_mfma_f32_16x16x32_bf16(af[mt], bkf[nt], accK[mt][nt], 0, 0, 0);
        accV[mt][nt] = __builtin_amdgcn_mfma_f32_16x16x32_bf16(af[mt], bvf[nt], accV[mt][nt], 0, 0, 0);
      }
  }

#pragma unroll
  for (int nt = 0; nt < 2; ++nt) {
    const int col = n0 + wn2 + nt * 16 + ln;
    const float bc = bk[col];
#pragma unroll
    for (int mt = 0; mt < 4; ++mt)
#pragma unroll
      for (int r = 0; r < 4; ++r) {
        const int row = m0 + wm + mt * 16 + qd * 4 + r;
        Ck[(size_t)row * 512 + col] = f2bf(accK[mt][nt][r] + bc);
      }
  }

  if constexpr (!TRANSV) {
#pragma unroll
    for (int nt = 0; nt < 2; ++nt) {
      const int col = n0 + wn2 + nt * 16 + ln;
      const float bc = bv[col];
#pragma unroll
      for (int mt = 0; mt < 4; ++mt)
#pragma unroll
        for (int r = 0; r < 4; ++r) {
          const int row = m0 + wm + mt * 16 + qd * 4 + r;
          Cvv[(size_t)row * 512 + col] = f2bf(accV[mt][nt][r] + bc);
        }
    }
  } else {
    __syncthreads();
    short* ep = &Sh[w * 1280];
    const int lr = lane >> 1, lc16 = (lane & 1) * 16;
#pragma unroll
    for (int pass = 0; pass < 2; ++pass) {
#pragma unroll
      for (int mh = 0; mh < 2; ++mh) {
        const int mt = pass * 2 + mh;
#pragma unroll
        for (int nt = 0; nt < 2; ++nt) {
          const float bc = bv[n0 + wn2 + nt * 16 + ln];
#pragma unroll
          for (int r = 0; r < 4; ++r)
            ep[(nt * 16 + ln) * 40 + mh * 16 + qd * 4 + r] = f2bf(accV[mt][nt][r] + bc);
        }
      }
      LGKM_WAIT();
      const int srow0 = m0 + wm + pass * 32;
      const int bidx = srow0 >> 11;
      const int sloc = (srow0 & 2047) + lc16;
      const int pcol = n0 + wn2 + lr;
      short* outp = Cvv + (size_t)bidx * P_ * S_ + (size_t)pcol * S_ + sloc;
      *(bf16x8*)outp = *(const bf16x8*)&ep[lr * 40 + lc16];
      *(bf16x8*)(outp + 8) = *(const bf16x8*)&ep[lr * 40 + lc16 + 8];
      LGKM_WAIT();
    }
  }
}

// ---------------------------------------------------------------------------
// split-K reduce for Wo: out = sum_z partial[z] + bo[col], fp32
// ---------------------------------------------------------------------------
__global__ __launch_bounds__(256) void reduce_wo(
    const float* __restrict__ partial, const float* __restrict__ bo,
    float* __restrict__ out)
{
  const int idx4 = blockIdx.x * 256 + threadIdx.x;
  float4 s = ((const float4*)bo)[idx4 & 127];
#pragma unroll
  for (int zz = 0; zz < 4; ++zz) {
    float4 p = ((const float4*)partial)[(size_t)zz * 262144 + idx4];
    s.x += p.x; s.y += p.y; s.z += p.z; s.w += p.w;
  }
  ((float4*)out)[idx4] = s;
}

// ---------------------------------------------------------------------------
// self-score + Ls zeroing
// ---------------------------------------------------------------------------
__global__ __launch_bounds__(256) void selfscore(
    const short* __restrict__ qb, const short* __restrict__ mkb,
    float* __restrict__ eself, float* __restrict__ Ls)
{
  const int z = blockIdx.x, t = threadIdx.x;
  const short* qr = qb + ((size_t)z * M_ + t) * P_;
  const short* mr = mkb + ((size_t)(z >> 3) * M_ + t) * P_;
  float s = 0.f;
#pragma unroll 8
  for (int c = 0; c < P_; c += 8) {
    bf16x8 qv = *(const bf16x8*)(qr + c);
    bf16x8 mv = *(const bf16x8*)(mr + c);
#pragma unroll
    for (int j = 0; j < 8; ++j) s += bf2f(qv[j]) * bf2f(mv[j]);
  }
  eself[(size_t)z * M_ + t] = __expf(s * SCALE);
  Ls[(size_t)z * M_ + t] = 0.f;
}

// ---------------------------------------------------------------------------
extern "C" void kernel_launch(void* const* d_in, const int* in_sizes, int n_in,
                              void* d_out, int out_size, void* d_ws, size_t ws_size,
                              hipStream_t stream) {
  const float* input_seq = (const float*)d_in[0];
  const float* memcells  = (const float*)d_in[1];
  const float* Wk = (const float*)d_in[2];
  const float* bk = (const float*)d_in[3];
  const float* Wv = (const float*)d_in[4];
  const float* bv = (const float*)d_in[5];
  const float* Wq = (const float*)d_in[6];
  const float* bq = (const float*)d_in[7];
  const float* Wo = (const float*)d_in[8];
  const float* bo = (const float*)d_in[9];
  float* out = (float*)d_out;

  short* ws = (short*)d_ws;
  size_t o = 0;
  short* valb = ws + o; o += (size_t)B_ * M_ * H_ * P_;      // 8388608
  short* WoT  = ws + o; o += (size_t)(H_ * P_) * P_;          // 2097152
  short* mvb  = ws + o; o += (size_t)B_ * M_ * P_;            // 1048576
  short* mkb  = ws + o; o += (size_t)B_ * M_ * P_;            // 1048576
  short* qb   = ws + o; o += (size_t)B_ * H_ * M_ * P_;       // 8388608
  short* ivT  = ws + o; o += (size_t)B_ * P_ * S_;            // 8388608
  short* ikb  = ws + o; o += (size_t)B_ * S_ * P_;            // 8388608
  float* partial = (float*)(ws + o); o += (size_t)B_ * H_ * M_ * P_;  // 16 MB
  float* eself = (float*)(ws + o); o += 2 * (size_t)B_ * H_ * M_;
  float* Ls    = (float*)(ws + o); o += 2 * (size_t)B_ * H_ * M_;
  short* region2 = ws + o;                                    // Eb region (64 MB)
  short* Ab  = region2;
  short* Mb  = Ab + (size_t)B_ * S_ * D_;
  short* WkT = Mb + (size_t)B_ * M_ * D_;
  short* WvT = WkT + (size_t)D_ * P_;
  short* WqT = WvT + (size_t)D_ * P_;
  short* Eb  = region2;   // overlaps the above (all dead before E is written)

  dim3 blk(256);

  const int n4A = B_ * S_ * D_ / 4;
  const int n4M = B_ * M_ * D_ / 4;
  cast_both<<<dim3((n4A + n4M) / 256), blk, 0, stream>>>(input_seq, Ab, n4A, memcells, Mb);
  wtrans_all<<<dim3(16, 16, 10), blk, 0, stream>>>(Wk, Wv, Wq, WkT, WvT, WqT);
  wtrans_wo<<<dim3(16, 128), blk, 0, stream>>>(Wo, WoT);

  proj_kv<true><<<dim3(8, 128), blk, 0, stream>>>(Ab, WkT, WvT, bk, bv, ikb, ivT);
  proj_kv<false><<<dim3(8, 16), blk, 0, stream>>>(Mb, WkT, WvT, bk, bv, mkb, mvb);

  // q projection: MODE 1, z = h
  gemm128<1, 512, 512, 512, 512><<<dim3(4, 16, 8), blk, 0, stream>>>(
      Mb, WqT, bq, qb, 0, (size_t)D_ * P_, 0, nullptr, nullptr, nullptr);

  // eself + zero Ls (before QK's atomics)
  selfscore<<<dim3(64), blk, 0, stream>>>(qb, mkb, eself, Ls);

  // E = exp(scale * q @ ik^T) + fused row-sum; per-batch 2048x2048, K=512
  // 128^2 tiles, 2048 blocks, 32 KiB LDS -> 3 blocks/CU
  qk128<16><<<dim3(8, 16, 16), blk, 0, stream>>>(qb, ikb, Eb, Ls);

  // val = normalize(E @ iv + eself*mv), concat layout; per-batch 2048x512,
  // K=2048; 128x64 tiles, 1024 blocks, 48 KiB LDS -> 3 blocks/CU
  pv64<32><<<dim3(8, 8, 16), blk, 0, stream>>>(Eb, ivT, valb, Ls, eself, mvb);

  // Wo: split-K=4 partials, then reduce+bias
  gemm128<5, 1024, 512, 4096, 4096><<<dim3(4, 16, 4), blk, 0, stream>>>(
      valb, WoT, nullptr, partial, 1024, 1024,
      (size_t)2048 * 512, nullptr, nullptr, nullptr);
  reduce_wo<<<dim3(1024), blk, 0, stream>>>(partial, bo, out);
}